// Round 9
// baseline (214.365 us; speedup 1.0000x reference)
//
#include <hip/hip_runtime.h>
#include <math.h>

// ---------- constants ----------
#define B_  2
#define T_  4096
#define DM  2048
#define H_  16
#define HKV 4
#define DV_ 64
#define MB_ 64
#define LW_ 1024
#define REMOTE 3072     // T - LW
#define NBLK 48         // REMOTE/MB
#define KTOT 1072       // NBLK + LW
#define NTILES 17       // ceil(1072/64)

typedef __bf16 bf16x8 __attribute__((ext_vector_type(8)));
typedef float  f32x4  __attribute__((ext_vector_type(4)));

__device__ __forceinline__ float bf2f(unsigned short u) {
    unsigned int x = ((unsigned int)u) << 16;
    return __builtin_bit_cast(float, x);
}
__device__ __forceinline__ unsigned short f2bf(float f) {
    unsigned int x = __builtin_bit_cast(unsigned int, f);
    x = x + 0x7fffu + ((x >> 16) & 1u);   // round-to-nearest-even
    return (unsigned short)(x >> 16);
}

// async global->LDS, 16B per lane; LDS dest = wave-uniform base + lane*16
__device__ __forceinline__ void gload16(const unsigned short* gsrc,
                                        unsigned short* ldst) {
    __builtin_amdgcn_global_load_lds(
        (const __attribute__((address_space(1))) void*)gsrc,
        (__attribute__((address_space(3))) void*)ldst,
        16, 0, 0);
}

// ---------- fp32 -> bf16 bulk convert ----------
__global__ void cvt_f32_to_bf16(const float* __restrict__ src,
                                unsigned short* __restrict__ dst, int n) {
    int i = (blockIdx.x * blockDim.x + threadIdx.x) * 4;
    if (i >= n) return;
    float4 v = *(const float4*)(src + i);
    ushort4 o;
    o.x = f2bf(v.x); o.y = f2bf(v.y); o.z = f2bf(v.z); o.w = f2bf(v.w);
    *(ushort4*)(dst + i) = o;
}

// ---------- transpose + convert: src[R][C] f32 -> dst[C][R] bf16 ----------
__global__ void transpose_cvt(const float* __restrict__ src,
                              unsigned short* __restrict__ dst, int R, int C) {
    __shared__ float tile[32][33];
    int ct = blockIdx.x, rt = blockIdx.y;
    int tx = threadIdx.x, ty = threadIdx.y;
    #pragma unroll
    for (int i = ty; i < 32; i += 8)
        tile[i][tx] = src[(size_t)(rt * 32 + i) * C + ct * 32 + tx];
    __syncthreads();
    #pragma unroll
    for (int i = ty; i < 32; i += 8)
        dst[(size_t)(ct * 32 + i) * R + rt * 32 + tx] = f2bf(tile[tx][i]);
}

// ---------- 256x256 8-wave MFMA GEMM: ring-4 LDS, counted vmcnt(8) --------
// C[M,N] = A[M,K] * BT[N,K]^T.  BK=32, ring-4 slots of (A 16KB + B 16KB) =
// 128 KiB, prefetch depth 3, 2 compute phases/K-tile (mf 0-3 | mf 4-7),
// ONE barrier + counted vmcnt(8) per tile (never 0 until tail).
// Race ledger: tile t issues into slot (t-1)%4 whose readers retired before
// the top barrier; per-wave vmcnt THEN barrier => slot(t+1) globally landed.
// LDS swizzle both-sides, involution key (row>>1)&3 (measured conflict-free).
// MODE 0 (proj): fused epilogue — RoPE on geo cols, KV mem-block pooling.
// MODE 1: plain f32 store (Wo GEMM)
template<int MODE>
__global__ __launch_bounds__(512, 2) void gemm8p(
    const unsigned short* __restrict__ A,
    const unsigned short* __restrict__ BT,
    float* __restrict__ outF,
    unsigned short* __restrict__ qcat,
    unsigned short* __restrict__ kp,    // [bg][key][64]
    unsigned short* __restrict__ vt,    // [bg][d][KTOT]
    int M, int N, int K, int nbx)
{
    extern __shared__ __align__(16) unsigned short lds[];  // 4 * 16384 ushorts

    const int tid = threadIdx.x;
    const int lane = tid & 63, w = tid >> 6;   // 8 waves: 2M x 4N
    const int wm = w >> 2, wn = w & 3;
    const int l15 = lane & 15, lg = lane >> 4;

    // bijective XCD swizzle (gridDim.x % 8 == 0)
    const int cpx = gridDim.x >> 3;
    const int swz = (blockIdx.x & 7) * cpx + (blockIdx.x >> 3);
    const int bx = swz % nbx, by = swz / nbx;
    const int row0 = by * 256, col0 = bx * 256;

    const unsigned short* Ag = A  + (size_t)row0 * K;
    const unsigned short* Bg = BT + (size_t)col0 * K;

    // staging: 1024 chunks(16B)/matrix/tile; thread covers chunks {tid,tid+512}
    // chunk i -> row i>>2, phys pos i&3; source logical col = (i&3)^((row>>1)&3)
    const int sr0 = w * 16 + (lane >> 2);       // rows 0-127 (j=0)
    const int sr1 = sr0 + 128;                  // rows 128-255 (j=1)
    const int sc0 = ((lane & 3) ^ ((sr0 >> 1) & 3)) << 3;   // == for sr1 too

    // swizzled ds_read in-row chunk: phys = lg ^ ((l15>>1)&3)
    const int rdsw = (lg ^ ((l15 >> 1) & 3)) << 3;
    const int aoff = (wm * 128 + l15) * 32 + rdsw;   // + mf*512
    const int boff = (wn * 64 + l15) * 32 + rdsw;    // + nf*512

    const int NT = K >> 5;
    f32x4 acc[8][4] = {};

    auto stageA = [&](int slot, int kk) {
        unsigned short* sa = lds + slot * 16384;
        gload16(Ag + (size_t)sr0 * K + kk + sc0, sa + w * 512);
        gload16(Ag + (size_t)sr1 * K + kk + sc0, sa + 4096 + w * 512);
    };
    auto stageB = [&](int slot, int kk) {
        unsigned short* sb = lds + slot * 16384 + 8192;
        gload16(Bg + (size_t)sr0 * K + kk + sc0, sb + w * 512);
        gload16(Bg + (size_t)sr1 * K + kk + sc0, sb + 4096 + w * 512);
    };

    // prologue: tiles 0,1,2 -> slots 0,1,2 (12 loads); wait tile 0 (oldest 4)
    stageA(0, 0);  stageB(0, 0);
    stageA(1, 32); stageB(1, 32);
    stageA(2, 64); stageB(2, 64);
    asm volatile("s_waitcnt vmcnt(8)" ::: "memory");

    for (int t = 0; t < NT; ++t) {
        __builtin_amdgcn_s_barrier();     // all waves retired slot(t) waits +
                                          // finished reading slot(t-1)
        const unsigned short* As_ = lds + (t & 3) * 16384;
        const unsigned short* Bs_ = As_ + 8192;
        const int wslot = (t + 3) & 3;    // == (t-1)%4, readers done
        const int kk3 = (t + 3) << 5;
        const bool st = (t + 3) < NT;

        // ---- phase 1: stage A(t+3) ; frags B + A(mf0-3) ; 16 MFMA ----
        if (st) stageA(wslot, kk3);
        bf16x8 bfr[4], af[4];
        #pragma unroll
        for (int nf = 0; nf < 4; nf++)
            bfr[nf] = __builtin_bit_cast(bf16x8, *(const uint4*)&Bs_[boff + nf * 512]);
        #pragma unroll
        for (int mf = 0; mf < 4; mf++)
            af[mf] = __builtin_bit_cast(bf16x8, *(const uint4*)&As_[aoff + mf * 512]);
        __builtin_amdgcn_s_setprio(1);
        #pragma unroll
        for (int mf = 0; mf < 4; mf++)
            #pragma unroll
            for (int nf = 0; nf < 4; nf++)
                acc[mf][nf] = __builtin_amdgcn_mfma_f32_16x16x32_bf16(
                                  af[mf], bfr[nf], acc[mf][nf], 0, 0, 0);
        __builtin_amdgcn_s_setprio(0);

        // ---- phase 2: stage B(t+3) ; frags A(mf4-7) ; 16 MFMA ----
        if (st) stageB(wslot, kk3);
        bf16x8 af2[4];
        #pragma unroll
        for (int mf = 0; mf < 4; mf++)
            af2[mf] = __builtin_bit_cast(bf16x8, *(const uint4*)&As_[aoff + (mf + 4) * 512]);
        __builtin_amdgcn_s_setprio(1);
        #pragma unroll
        for (int mf = 0; mf < 4; mf++)
            #pragma unroll
            for (int nf = 0; nf < 4; nf++)
                acc[mf + 4][nf] = __builtin_amdgcn_mfma_f32_16x16x32_bf16(
                                      af2[mf], bfr[nf], acc[mf + 4][nf], 0, 0, 0);
        __builtin_amdgcn_s_setprio(0);

        // counted drain: slot(t+1)'s 4 loads retired; 8 newer stay in flight
        if (t + 3 < NT)      asm volatile("s_waitcnt vmcnt(8)" ::: "memory");
        else if (t + 2 < NT) asm volatile("s_waitcnt vmcnt(4)" ::: "memory");
        else if (t + 1 < NT) asm volatile("s_waitcnt vmcnt(0)" ::: "memory");
    }

    // ---- epilogue ----
    const int rbase = wm * 128;
    if (MODE == 1) {
        #pragma unroll
        for (int mf = 0; mf < 8; mf++)
            #pragma unroll
            for (int nf = 0; nf < 4; nf++)
                #pragma unroll
                for (int r = 0; r < 4; r++) {
                    int row = row0 + rbase + mf * 16 + lg * 4 + r;
                    int col = col0 + wn * 64 + nf * 16 + l15;
                    outF[(size_t)row * N + col] = acc[mf][nf][r];
                }
    } else {
        const int cspan = col0 + wn * 64;       // wave col base (64-aligned)
        const int tbase = row0 & 4095;          // 256-tile never crosses b
        const int bq = row0 >> 12;

        // RoPE on geo spans: pair (d, d+16) == (nf, nf+1) in-fragment
        if ((cspan >= 512 && cspan < 1024) || (cspan >= 1152 && cspan < 1280)) {
            const float invf = exp2f(-(float)l15 * 0.8304820237218406f);
            #pragma unroll
            for (int mf = 0; mf < 8; mf++) {
                #pragma unroll
                for (int r = 0; r < 4; r++) {
                    float s, c;
                    sincosf((float)(tbase + rbase + mf*16 + lg*4 + r) * invf, &s, &c);
                    float a0 = acc[mf][0][r], a1 = acc[mf][1][r];
                    acc[mf][0][r] = a0 * c - a1 * s;
                    acc[mf][1][r] = a1 * c + a0 * s;
                    float a2 = acc[mf][2][r], a3 = acc[mf][3][r];
                    acc[mf][2][r] = a2 * c - a3 * s;
                    acc[mf][3][r] = a3 * c + a2 * s;
                }
            }
        }

        if (cspan < 1024) {
            // ---- Q -> qcat [b][h][t][64] ----
            #pragma unroll
            for (int nf = 0; nf < 4; nf++) {
                int col = cspan + nf * 16 + l15;
                int h = (col < 512) ? (col >> 5) : ((col - 512) >> 5);
                int d = (col < 512) ? (col & 31) : (32 + (col & 31));
                unsigned short* qb =
                    qcat + (((size_t)(bq * 16 + h)) * 4096 + tbase) * 64 + d;
                #pragma unroll
                for (int mf = 0; mf < 8; mf++)
                    #pragma unroll
                    for (int r = 0; r < 4; r++)
                        qb[(size_t)(rbase + mf*16 + lg*4 + r) * 64] =
                            f2bf(acc[mf][nf][r]);
            }
        } else if (tbase >= REMOTE) {
            // ---- local K/V rows -> full-res keys 48..1071 ----
            #pragma unroll
            for (int nf = 0; nf < 4; nf++) {
                int col = cspan + nf * 16 + l15;
                #pragma unroll
                for (int mf = 0; mf < 8; mf++)
                    #pragma unroll
                    for (int r = 0; r < 4; r++) {
                        int key = tbase + rbase + mf*16 + lg*4 + r - 3024;
                        unsigned short hv = f2bf(acc[mf][nf][r]);
                        if (col < 1280) {
                            int g, dk;
                            if (col < 1152) { g = (col - 1024) >> 5; dk = col & 31; }
                            else            { g = (col - 1152) >> 5; dk = 32 + (col & 31); }
                            kp[(((size_t)(bq*4 + g)) * KTOT + key) * 64 + dk] = hv;
                        } else {
                            int g = (col - 1280) >> 6, dv = col & 63;
                            vt[(((size_t)(bq*4 + g)) * 64 + dv) * KTOT + key] = hv;
                        }
                    }
            }
        } else {
            // ---- remote K/V rows -> pooled; mf-halves = two 64-row blocks ----
            #pragma unroll
            for (int half = 0; half < 2; half++) {
                #pragma unroll
                for (int nf = 0; nf < 4; nf++) {
                    float ps = 0.f;
                    #pragma unroll
                    for (int mf = half * 4; mf < half * 4 + 4; mf++)
                        #pragma unroll
                        for (int r = 0; r < 4; r++) ps += acc[mf][nf][r];
                    ps += __shfl_xor(ps, 16);
                    ps += __shfl_xor(ps, 32);
                    if (lane < 16) {
                        int col = cspan + nf * 16 + l15;
                        int key = ((tbase + rbase) >> 6) + half;
                        unsigned short hv = f2bf(ps * (1.f / 64.f));
                        if (col < 1280) {
                            int g, dk;
                            if (col < 1152) { g = (col - 1024) >> 5; dk = col & 31; }
                            else            { g = (col - 1152) >> 5; dk = 32 + (col & 31); }
                            kp[(((size_t)(bq*4 + g)) * KTOT + key) * 64 + dk] = hv;
                        } else {
                            int g = (col - 1280) >> 6, dv = col & 63;
                            vt[(((size_t)(bq*4 + g)) * 64 + dv) * KTOT + key] = hv;
                        }
                    }
                }
            }
        }
    }
}

// ---------- MFMA flash attention, wave-independent (NO barriers) ----------
__global__ __launch_bounds__(256) void attn_fwd(
    const unsigned short* __restrict__ qcat,
    const unsigned short* __restrict__ kp,   // [bg][key][64]
    const unsigned short* __restrict__ vt,   // [bg][d][KTOT]
    const float* __restrict__ ls,
    unsigned short* __restrict__ attn_out)
{
    __shared__ unsigned short Pl[4][32][72];   // per-wave P tile (bf16)

    const int tid = threadIdx.x;
    const int lane = tid & 63, w = tid >> 6;
    const int l15 = lane & 15, lg = lane >> 4;

    const int wid = blockIdx.x * 4 + w;        // 0..4095
    const int hb = wid & 31;
    const int iu = wid >> 5;                   // schedule slot 0..127
    int i;
    if (iu < 32)       i = 127 - iu;
    else if (iu == 32) i = 0;
    else if (iu == 33) i = 1;
    else               i = iu - 32;
    const int h = hb & 15, b = hb >> 4, g = h >> 2;
    const int q0 = i * 32;

    int ktmax;
    if (q0 < 64) ktmax = NTILES;               // uniform rows: all keys
    else {
        int lastkey = q0 + 31 - 3024;          // max valid local key index
        ktmax = (lastkey < NBLK) ? 1 : (lastkey / 64 + 1);
    }

    const float sc = __expf(ls[h]) * 0.17677669529663687f;   // exp(ls)/sqrt(32)

    bf16x8 aq[2][2];
    const unsigned short* qbase = qcat + (((size_t)(b * 16 + h)) * T_ + q0) * 64;
    #pragma unroll
    for (int rf = 0; rf < 2; rf++)
        #pragma unroll
        for (int kh = 0; kh < 2; kh++)
            aq[rf][kh] = __builtin_bit_cast(bf16x8,
                *(const uint4*)(qbase + (size_t)(rf*16 + l15)*64 + kh*32 + lg*8));

    float m[2][4], lrun[2][4];
    #pragma unroll
    for (int rf = 0; rf < 2; rf++)
        #pragma unroll
        for (int r = 0; r < 4; r++) { m[rf][r] = -1e9f; lrun[rf][r] = 0.f; }
    f32x4 oacc[2][4] = {};

    const unsigned short* kbase = kp + ((size_t)(b * 4 + g)) * KTOT * 64;
    const unsigned short* vbase = vt + ((size_t)(b * 4 + g)) * 64 * KTOT;

    for (int kt = 0; kt < ktmax; kt++) {
        const int kb = kt * 64;

        bf16x8 bk[4][2];
        #pragma unroll
        for (int nf = 0; nf < 4; nf++) {
            int krow = kb + nf*16 + l15;
            int krc = krow < KTOT ? krow : KTOT - 1;     // clamp (masked later)
            #pragma unroll
            for (int kh = 0; kh < 2; kh++)
                bk[nf][kh] = __builtin_bit_cast(bf16x8,
                    *(const uint4*)(kbase + (size_t)krc * 64 + kh*32 + lg*8));
        }

        f32x4 s[2][4] = {};
        #pragma unroll
        for (int rf = 0; rf < 2; rf++)
            #pragma unroll
            for (int nf = 0; nf < 4; nf++)
                #pragma unroll
                for (int kh = 0; kh < 2; kh++)
                    s[rf][nf] = __builtin_amdgcn_mfma_f32_16x16x32_bf16(
                                    aq[rf][kh], bk[nf][kh], s[rf][nf], 0, 0, 0);

        bf16x8 bv[4][2];
        #pragma unroll
        for (int nfv = 0; nfv < 4; nfv++)
            #pragma unroll
            for (int kh = 0; kh < 2; kh++) {
                int kc = kb + kh*32 + lg*8;
                int kcc = (kc + 8 <= KTOT) ? kc : KTOT - 8;  // clamp (P=0 there)
                bv[nfv][kh] = __builtin_bit_cast(bf16x8,
                    *(const uint4*)(vbase + (size_t)(nfv*16 + l15) * KTOT + kcc));
            }

        #pragma unroll
        for (int rf = 0; rf < 2; rf++) {
            #pragma unroll
            for (int r = 0; r < 4; r++) {
                const int qpos = q0 + rf*16 + lg*4 + r;
                float vals[4];
                float tmax = -INFINITY;
                #pragma unroll
                for (int nf = 0; nf < 4; nf++) {
                    int key = kb + nf*16 + l15;
                    float v = s[rf][nf][r] * sc;
                    int kpos = (key < NBLK) ? key * 64 + 63 : 3024 + key;
                    v = (key < KTOT) ? ((kpos <= qpos) ? v : -1e9f) : -INFINITY;
                    vals[nf] = v;
                    tmax = fmaxf(tmax, v);
                }
                #pragma unroll
                for (int d = 1; d < 16; d <<= 1)
                    tmax = fmaxf(tmax, __shfl_xor(tmax, d));
                float mn = fmaxf(m[rf][r], tmax);
                float scl = __expf(m[rf][r] - mn);
                m[rf][r] = mn;
                float rs = 0.f;
                #pragma unroll
                for (int nf = 0; nf < 4; nf++) {
                    unsigned short pb = f2bf(__expf(vals[nf] - mn));
                    rs += bf2f(pb);          // sum the ROUNDED p: exact convex comb
                    Pl[w][rf*16 + lg*4 + r][nf*16 + l15] = pb;
                }
                #pragma unroll
                for (int d = 1; d < 16; d <<= 1)
                    rs += __shfl_xor(rs, d);
                lrun[rf][r] = lrun[rf][r] * scl + rs;
                #pragma unroll
                for (int nfv = 0; nfv < 4; nfv++)
                    oacc[rf][nfv][r] *= scl;
            }
        }

        #pragma unroll
        for (int rf = 0; rf < 2; rf++) {
            bf16x8 pa[2];
            #pragma unroll
            for (int kh = 0; kh < 2; kh++)
                pa[kh] = __builtin_bit_cast(bf16x8,
                    *(const uint4*)&Pl[w][rf*16 + l15][kh*32 + lg*8]);
            #pragma unroll
            for (int nfv = 0; nfv < 4; nfv++)
                #pragma unroll
                for (int kh = 0; kh < 2; kh++)
                    oacc[rf][nfv] = __builtin_amdgcn_mfma_f32_16x16x32_bf16(
                                        pa[kh], bv[nfv][kh], oacc[rf][nfv], 0, 0, 0);
        }
    }

    #pragma unroll
    for (int rf = 0; rf < 2; rf++) {
        #pragma unroll
        for (int r = 0; r < 4; r++) {
            float inv = 1.f / lrun[rf][r];
            int q = q0 + rf*16 + lg*4 + r;
            size_t obase = ((size_t)(b * T_ + q)) * 1024 + h * 64;
            #pragma unroll
            for (int nfv = 0; nfv < 4; nfv++)
                attn_out[obase + nfv*16 + l15] = f2bf(oacc[rf][nfv][r] * inv);
        }
    }
}

// ---------- host launch ----------
extern "C" void kernel_launch(void* const* d_in, const int* in_sizes, int n_in,
                              void* d_out, int out_size, void* d_ws, size_t ws_size,
                              hipStream_t stream) {
    const float* x      = (const float*)d_in[0];
    const float* Wq_sem = (const float*)d_in[1];
    const float* Wk_sem = (const float*)d_in[2];
    const float* Wq_geo = (const float*)d_in[3];
    const float* Wk_geo = (const float*)d_in[4];
    const float* Wv     = (const float*)d_in[5];
    const float* Wo     = (const float*)d_in[6];
    const float* ls     = (const float*)d_in[7];

    char* w = (char*)d_ws;
    auto alloc = [&](size_t bytes) {
        char* p = w;
        w += (bytes + 255) & ~(size_t)255;
        return p;
    };
    unsigned short* xb    = (unsigned short*)alloc((size_t)8192 * 2048 * 2);
    unsigned short* WcatT = (unsigned short*)alloc((size_t)1536 * 2048 * 2);
    unsigned short* WoT   = (unsigned short*)alloc((size_t)2048 * 1024 * 2);
    unsigned short* qcat  = (unsigned short*)alloc((size_t)2 * 16 * 4096 * 64 * 2);
    unsigned short* kp    = (unsigned short*)alloc((size_t)2 * 4 * 1072 * 64 * 2);
    unsigned short* vt    = (unsigned short*)alloc((size_t)2 * 4 * 1072 * 64 * 2);
    unsigned short* aout  = (unsigned short*)alloc((size_t)8192 * 1024 * 2);

    // allow 128 KiB dynamic LDS (idempotent)
    hipFuncSetAttribute(reinterpret_cast<const void*>(&gemm8p<0>),
                        hipFuncAttributeMaxDynamicSharedMemorySize, 131072);
    hipFuncSetAttribute(reinterpret_cast<const void*>(&gemm8p<1>),
                        hipFuncAttributeMaxDynamicSharedMemorySize, 131072);

    // 1) x -> bf16
    cvt_f32_to_bf16<<<16384, 256, 0, stream>>>(x, xb, 8192 * 2048);

    // 2) weights -> bf16, transposed to [N][K]
    dim3 tb(32, 8);
    transpose_cvt<<<dim3(16, 64), tb, 0, stream>>>(Wq_sem, WcatT + (size_t)0    * 2048, 2048, 512);
    transpose_cvt<<<dim3(16, 64), tb, 0, stream>>>(Wq_geo, WcatT + (size_t)512  * 2048, 2048, 512);
    transpose_cvt<<<dim3( 4, 64), tb, 0, stream>>>(Wk_sem, WcatT + (size_t)1024 * 2048, 2048, 128);
    transpose_cvt<<<dim3( 4, 64), tb, 0, stream>>>(Wk_geo, WcatT + (size_t)1152 * 2048, 2048, 128);
    transpose_cvt<<<dim3( 8, 64), tb, 0, stream>>>(Wv,     WcatT + (size_t)1280 * 2048, 2048, 256);
    transpose_cvt<<<dim3(64, 32), tb, 0, stream>>>(Wo, WoT, 1024, 2048);

    // 3) fused projection GEMM (+RoPE +pooling) -> qcat / kp / vt
    gemm8p<0><<<192, 512, 131072, stream>>>(
        xb, WcatT, nullptr, qcat, kp, vt, 8192, 1536, 2048, 6);

    // 4) wave-independent MFMA flash attention
    attn_fwd<<<dim3(1024), 256, 0, stream>>>(qcat, kp, vt, ls, aout);

    // 5) output projection -> d_out (fp32)
    gemm8p<1><<<256, 512, 131072, stream>>>(
        aout, WoT, (float*)d_out, nullptr, nullptr, nullptr, 8192, 2048, 1024, 8);
}